// Round 2
// baseline (107.469 us; speedup 1.0000x reference)
//
#include <hip/hip_runtime.h>

#define VOCAB  100000
#define EMB    300
#define BATCH  16384
#define TOTAL  65536
#define NG     5
#define CHUNKS 75                  // EMB/4 float4 chunks per row (1200 B)

#define NBLK_A 4096                // 4 segments per block (4 waves)
#define NBLK_B 28800               // 98304 rows * 75 chunks / 256 threads
#define NBLK   (NBLK_A + NBLK_B)   // 32896
#define A_SPAN (NBLK_A * 8)        // A-blocks interleaved every 8th block

typedef float f4 __attribute__((ext_vector_type(4)));

// 64-ary cooperative lower_bound over sorted seg_ids[0..TOTAL):
// 3 dependent load+ballot rounds instead of ~17 serial binary-search steps.
__device__ __forceinline__ int lb64(const int* __restrict__ seg, int v, int lane) {
    int base = 0;
    unsigned long long m;
    // level 1: 64 chunks of 1024, probe each chunk's last element
    int p = lane * 1024 + 1023;
    m = __ballot(seg[p] < v);
    base += (int)__popcll(m) << 10;
    // level 2: 64 chunks of 16
    p = base + lane * 16 + 15;
    m = __ballot((p < TOTAL) && (seg[p] < v));
    base += (int)__popcll(m) << 4;
    // level 3: linear over the last 16
    p = base + lane;
    m = __ballot((lane < 16) && (p < TOTAL) && (seg[p] < v));
    base += (int)__popcll(m);
    return base;
}

__global__ __launch_bounds__(256) void fused_kernel(
    const float* __restrict__ W_in,
    const float* __restrict__ W_out,
    const int*   __restrict__ flat_idx,
    const int*   __restrict__ seg_ids,
    const int*   __restrict__ out_idx,
    const int*   __restrict__ ng_idx,
    float*       __restrict__ in_vec,
    float*       __restrict__ out_vec,
    float*       __restrict__ neg_vec)
{
    const unsigned bid = blockIdx.x;

    if (bid < A_SPAN && (bid & 7u) == 0u) {
        // ---------- A: fused gather + segment_sum, one wave per segment ----------
        const int aid  = (int)(bid >> 3);          // 0..NBLK_A-1
        const int wid  = threadIdx.x >> 6;
        const int lane = threadIdx.x & 63;
        const int seg  = aid * 4 + wid;

        const int start = lb64(seg_ids, seg,     lane);
        const int end   = lb64(seg_ids, seg + 1, lane);

        f4 acc0 = {0.f, 0.f, 0.f, 0.f};
        f4 acc1 = {0.f, 0.f, 0.f, 0.f};
        const bool extra = lane < (CHUNKS - 64);   // lanes 0..10 own chunk 64+lane

        for (int t0 = start; t0 < end; t0 += 64) {
            const int n = min(64, end - t0);
            // batch-load up to 64 token indices, broadcast via shfl
            const int myidx = (lane < n) ? flat_idx[t0 + lane] : 0;
            for (int j = 0; j < n; ++j) {
                const int idx = __shfl(myidx, j);
                const f4* row = reinterpret_cast<const f4*>(W_in + (size_t)idx * EMB);
                acc0 += row[lane];
                if (extra) acc1 += row[lane + 64];
            }
        }

        f4* dst = reinterpret_cast<f4*>(in_vec + (size_t)seg * EMB);
        __builtin_nontemporal_store(acc0, dst + lane);     // empty segment -> zeros
        if (extra) __builtin_nontemporal_store(acc1, dst + lane + 64);
    } else {
        // ---------- B: plain row gathers (out_vec + neg_vec) ----------
        const int b = (bid < A_SPAN) ? (int)(bid - (bid >> 3) - 1u)
                                     : (int)(NBLK_A * 7 + (bid - A_SPAN));
        const int gid = b * 256 + (int)threadIdx.x;        // exactly 7,372,800 total
        const int row = gid / CHUNKS;
        const int c   = gid - row * CHUNKS;

        int idx;
        float* dstbase;
        if (row < BATCH) {
            idx = out_idx[row];
            dstbase = out_vec + (size_t)row * EMB;
        } else {
            const int rr = row - BATCH;
            idx = ng_idx[rr];
            dstbase = neg_vec + (size_t)rr * EMB;
        }

        const f4* src = reinterpret_cast<const f4*>(W_out + (size_t)idx * EMB);
        const f4 v = src[c];
        __builtin_nontemporal_store(v, reinterpret_cast<f4*>(dstbase) + c);
    }
}

extern "C" void kernel_launch(void* const* d_in, const int* in_sizes, int n_in,
                              void* d_out, int out_size, void* d_ws, size_t ws_size,
                              hipStream_t stream)
{
    const float* W_in   = (const float*)d_in[0];
    const float* W_out  = (const float*)d_in[1];
    const int*   flat   = (const int*)d_in[2];
    const int*   segids = (const int*)d_in[3];
    const int*   outidx = (const int*)d_in[4];
    const int*   ngidx  = (const int*)d_in[5];

    float* o       = (float*)d_out;
    float* in_vec  = o;                                  // [BATCH, EMB]
    float* out_vec = o + (size_t)BATCH * EMB;            // [BATCH, EMB]
    float* neg_vec = o + (size_t)2 * BATCH * EMB;        // [BATCH, NG, EMB]

    fused_kernel<<<NBLK, 256, 0, stream>>>(W_in, W_out, flat, segids,
                                           outidx, ngidx, in_vec, out_vec, neg_vec);
}

// Round 3
// 70.744 us; speedup vs baseline: 1.5191x; 1.5191x over previous
//
#include <hip/hip_runtime.h>

#define VOCAB  100000
#define EMB    300
#define BATCH  16384
#define TOTAL  65536
#define NG     5
#define CHUNKS 75                  // EMB/4 float4 chunks per row (1200 B)

typedef float f4 __attribute__((ext_vector_type(4)));

// 64-ary cooperative lower_bound over sorted seg_ids[0..TOTAL):
// 3 dependent load+ballot rounds instead of ~17 serial binary-search steps.
__device__ __forceinline__ int lb64(const int* __restrict__ seg, int v, int lane) {
    int base = 0;
    unsigned long long m;
    // level 1: 64 chunks of 1024, probe each chunk's last element
    int p = lane * 1024 + 1023;
    m = __ballot(seg[p] < v);
    base += (int)__popcll(m) << 10;
    // level 2: 64 chunks of 16
    p = base + lane * 16 + 15;
    m = __ballot((p < TOTAL) && (seg[p] < v));
    base += (int)__popcll(m) << 4;
    // level 3: linear over the last 16
    p = base + lane;
    m = __ballot((lane < 16) && (p < TOTAL) && (seg[p] < v));
    base += (int)__popcll(m);
    return base;
}

// ---------------- Kernel A: fused gather + segment_sum ----------------
// One 64-lane wave per segment (4 waves/block). Lane i owns float4 chunk i,
// lanes 0..10 also own chunk 64+i.
__global__ __launch_bounds__(256) void segsum_kernel(
    const float* __restrict__ W_in,
    const int*   __restrict__ flat_idx,
    const int*   __restrict__ seg_ids,
    float*       __restrict__ in_vec)
{
    const int wid  = threadIdx.x >> 6;
    const int lane = threadIdx.x & 63;
    const int seg  = blockIdx.x * 4 + wid;

    const int start = lb64(seg_ids, seg,     lane);
    const int end   = lb64(seg_ids, seg + 1, lane);

    f4 acc0 = {0.f, 0.f, 0.f, 0.f};
    f4 acc1 = {0.f, 0.f, 0.f, 0.f};
    const bool extra = lane < (CHUNKS - 64);   // lanes 0..10

    for (int t0 = start; t0 < end; t0 += 64) {
        const int n = min(64, end - t0);
        // batch-load up to 64 token indices, broadcast via shfl
        const int myidx = (lane < n) ? flat_idx[t0 + lane] : 0;
        for (int j = 0; j < n; ++j) {
            const int idx = __shfl(myidx, j);
            const f4* row = reinterpret_cast<const f4*>(W_in + (size_t)idx * EMB);
            acc0 += row[lane];
            if (extra) acc1 += row[lane + 64];
        }
    }

    f4* dst = reinterpret_cast<f4*>(in_vec + (size_t)seg * EMB);
    dst[lane] = acc0;                 // empty segment -> zeros (segment_sum semantics)
    if (extra) dst[lane + 64] = acc1;
}

// ---------------- Kernel B: plain row gathers (out_vec + neg_vec) ----------------
// One thread per float4 chunk; rows 0..BATCH-1 -> out_vec, rest -> neg_vec.
__global__ __launch_bounds__(256) void gather_kernel(
    const float* __restrict__ W_out,
    const int*   __restrict__ out_idx,
    const int*   __restrict__ ng_idx,
    float*       __restrict__ out_vec,
    float*       __restrict__ neg_vec)
{
    const int gid = blockIdx.x * blockDim.x + threadIdx.x;
    const int total_chunks = (BATCH + BATCH * NG) * CHUNKS;  // 7,372,800
    if (gid >= total_chunks) return;

    const int row = gid / CHUNKS;    // magic-mul div by constant
    const int c   = gid - row * CHUNKS;

    int idx;
    float* dst;
    if (row < BATCH) {
        idx = out_idx[row];
        dst = out_vec + (size_t)row * EMB;
    } else {
        const int rr = row - BATCH;
        idx = ng_idx[rr];
        dst = neg_vec + (size_t)rr * EMB;
    }

    const f4* src = reinterpret_cast<const f4*>(W_out + (size_t)idx * EMB);
    reinterpret_cast<f4*>(dst)[c] = src[c];
}

extern "C" void kernel_launch(void* const* d_in, const int* in_sizes, int n_in,
                              void* d_out, int out_size, void* d_ws, size_t ws_size,
                              hipStream_t stream)
{
    const float* W_in   = (const float*)d_in[0];
    const float* W_out  = (const float*)d_in[1];
    const int*   flat   = (const int*)d_in[2];
    const int*   segids = (const int*)d_in[3];
    const int*   outidx = (const int*)d_in[4];
    const int*   ngidx  = (const int*)d_in[5];

    float* o       = (float*)d_out;
    float* in_vec  = o;                                  // [BATCH, EMB]
    float* out_vec = o + (size_t)BATCH * EMB;            // [BATCH, EMB]
    float* neg_vec = o + (size_t)2 * BATCH * EMB;        // [BATCH, NG, EMB]

    // Kernel A: one wave per segment, 4 segments per block
    segsum_kernel<<<BATCH / 4, 256, 0, stream>>>(W_in, flat, segids, in_vec);

    // Kernel B: one thread per float4 chunk
    const int total_chunks = (BATCH + BATCH * NG) * CHUNKS;   // 7,372,800
    const int blocks = (total_chunks + 255) / 256;            // 28,800
    gather_kernel<<<blocks, 256, 0, stream>>>(W_out, outidx, ngidx, out_vec, neg_vec);
}